// Round 12
// baseline (178.343 us; speedup 1.0000x reference)
//
#include <hip/hip_runtime.h>

#define S 4096
#define PS 4128            // padded hT row stride in elems (breaks 8KB L1 aliasing)
#define FIN 128
#define FOUT 64
#define H 8
#define ALPHA 0.2f

typedef __attribute__((ext_vector_type(2)))  _Float16 f16x2;
typedef __attribute__((ext_vector_type(8)))  _Float16 f16x8;
typedef __attribute__((ext_vector_type(16))) float    f32x16;

__device__ __forceinline__ unsigned short f2h(float x) {
    return __builtin_bit_cast(unsigned short, (_Float16)x);  // RTNE
}

// ---------------------------------------------------------------------------
// k_proj: h = X·W (fp32), hT[h][f][j] fp16 with padded row stride PS;
// f1=h·a1, f2=h·a2 -> E1h[i][h]=(e^f1,e^{a f1}); E2p[h][j]=(e^f2,e^{a f2}).
// ---------------------------------------------------------------------------
__global__ __launch_bounds__(256) void k_proj(const float* __restrict__ X,
                                              const float* __restrict__ W,
                                              const float* __restrict__ a1,
                                              const float* __restrict__ a2,
                                              unsigned short* __restrict__ hT,
                                              float2* __restrict__ E1h,
                                              float2* __restrict__ E2p) {
    __shared__ float xs[64][36];
    __shared__ float Ws[32][68];
    const int h  = blockIdx.y;
    const int j0 = blockIdx.x * 64;
    const int t  = threadIdx.x;
    const int fg = t & 15, rg = t >> 4;
    const int jr = t >> 2, q = t & 3;
    const int kw = t >> 3, cw = t & 7;
    float acc[4][4] = {};
#pragma unroll
    for (int k0 = 0; k0 < FIN; k0 += 32) {
        *(float4*)&xs[jr][q * 8]      = *(const float4*)&X[(j0 + jr) * FIN + k0 + q * 8];
        *(float4*)&xs[jr][q * 8 + 4]  = *(const float4*)&X[(j0 + jr) * FIN + k0 + q * 8 + 4];
        *(float4*)&Ws[kw][cw * 8]     = *(const float4*)&W[(h * FIN + k0 + kw) * FOUT + cw * 8];
        *(float4*)&Ws[kw][cw * 8 + 4] = *(const float4*)&W[(h * FIN + k0 + kw) * FOUT + cw * 8 + 4];
        __syncthreads();
#pragma unroll
        for (int kc = 0; kc < 8; ++kc) {
            float4 xr[4], wr[4];
#pragma unroll
            for (int r = 0; r < 4; ++r) xr[r] = *(const float4*)&xs[4 * rg + r][kc * 4];
#pragma unroll
            for (int kk = 0; kk < 4; ++kk) wr[kk] = *(const float4*)&Ws[kc * 4 + kk][fg * 4];
#pragma unroll
            for (int r = 0; r < 4; ++r) {
                const float* xp = (const float*)&xr[r];
#pragma unroll
                for (int kk = 0; kk < 4; ++kk) {
                    const float xv = xp[kk];
                    acc[r][0] += xv * wr[kk].x;
                    acc[r][1] += xv * wr[kk].y;
                    acc[r][2] += xv * wr[kk].z;
                    acc[r][3] += xv * wr[kk].w;
                }
            }
        }
        __syncthreads();
    }
    const float4 a1v = *(const float4*)&a1[h * FOUT + fg * 4];
    const float4 a2v = *(const float4*)&a2[h * FOUT + fg * 4];
#pragma unroll
    for (int r = 0; r < 4; ++r) {
        float p1 = acc[r][0] * a1v.x + acc[r][1] * a1v.y + acc[r][2] * a1v.z + acc[r][3] * a1v.w;
        float p2 = acc[r][0] * a2v.x + acc[r][1] * a2v.y + acc[r][2] * a2v.z + acc[r][3] * a2v.w;
#pragma unroll
        for (int off = 1; off < 16; off <<= 1) {
            p1 += __shfl_xor(p1, off, 64);
            p2 += __shfl_xor(p2, off, 64);
        }
        if (fg == 0) {
            const int row = j0 + 4 * rg + r;
            E1h[(size_t)row * H + h] = make_float2(__expf(p1), __expf(ALPHA * p1));
            E2p[h * S + row]         = make_float2(__expf(p2), __expf(ALPHA * p2));
        }
    }
#pragma unroll
    for (int c = 0; c < 4; ++c) {
        ushort4 pk;
        pk.x = f2h(acc[0][c]);
        pk.y = f2h(acc[1][c]);
        pk.z = f2h(acc[2][c]);
        pk.w = f2h(acc[3][c]);
        *(ushort4*)&hT[(size_t)(h * FOUT + fg * 4 + c) * PS + j0 + 4 * rg] = pk;
    }
}

// ---------------------------------------------------------------------------
// k_colsum: Dpart[z,h,j] = sum_{i in chunk z} adj(i,j)*max(E1x*E2x, E1y*E2y);
// packs adj into TRANSPOSED bitmask bmT[jword][i]. 8 adj rows in flight/wave,
// 2048 blocks = 8/CU. grid (S/64, S/128), 256 thr, 32 rows/wave.
// ---------------------------------------------------------------------------
__global__ __launch_bounds__(256) void k_colsum(const int* __restrict__ adj,
                                                const float2* __restrict__ E1h,
                                                const float2* __restrict__ E2p,
                                                float* __restrict__ Dpart,
                                                unsigned int* __restrict__ bmT) {
    __shared__ float red[4][H][64];
    const int j0    = blockIdx.x * 64;
    const int ibase = blockIdx.y * 128;
    const int t  = threadIdx.x;
    const int jl = t & 63;
    const int wv = __builtin_amdgcn_readfirstlane(t >> 6);
    float2 e2v[H];
    float Dl[H];
#pragma unroll
    for (int hh = 0; hh < H; ++hh) { e2v[hh] = E2p[hh * S + j0 + jl]; Dl[hh] = 0.f; }
    const int rowbase = ibase + wv * 32;
    for (int s = 0; s < 32; s += 8) {
        int av[8];
#pragma unroll
        for (int u = 0; u < 8; ++u)
            av[u] = adj[(size_t)(rowbase + s + u) * S + j0 + jl];
#pragma unroll
        for (int u = 0; u < 8; ++u) {
            const int row = rowbase + s + u;
            const float2* __restrict__ e1r = E1h + (size_t)row * H;  // wave-uniform
            const unsigned long long blt = __ballot(av[u] != 0);
            if (jl == 0) {
                bmT[(j0 >> 5) * S + row]       = (unsigned int)blt;
                bmT[((j0 >> 5) + 1) * S + row] = (unsigned int)(blt >> 32);
            }
            const float bf = av[u] != 0 ? 1.f : 0.f;
#pragma unroll
            for (int hh = 0; hh < H; ++hh) {
                const float2 e1 = e1r[hh];
                Dl[hh] = fmaf(bf, fmaxf(e1.x * e2v[hh].x, e1.y * e2v[hh].y), Dl[hh]);
            }
        }
    }
#pragma unroll
    for (int hh = 0; hh < H; ++hh) red[wv][hh][jl] = Dl[hh];
    __syncthreads();
    if (wv == 0) {
#pragma unroll
        for (int hh = 0; hh < H; ++hh) {
            const float sum = red[0][hh][jl] + red[1][hh][jl] +
                              red[2][hh][jl] + red[3][hh][jl];
            Dpart[(blockIdx.y * H + hh) * S + j0 + jl] = sum;
        }
    }
}

// ---------------------------------------------------------------------------
// k_finish: wE2h[h][pair] = { h2(qx_j,qx_j1), h2(qy_j,qy_j1) },
// q = E2pair / colsum  (w folded in, packed fp16 SoA pairs for k_attn)
// ---------------------------------------------------------------------------
__global__ __launch_bounds__(256) void k_finish(const float* __restrict__ Dpart,
                                                const float2* __restrict__ E2p,
                                                uint2* __restrict__ wE2h) {
    const int idx = blockIdx.x * 256 + threadIdx.x;   // pair index over H*S/2
    const int hh = idx >> 11, pp = idx & 2047;
    const int j = 2 * pp;
    float sx = 0.f, sy = 0.f;
#pragma unroll
    for (int z = 0; z < 32; ++z) {
        const float2 d = *(const float2*)&Dpart[(z * H + hh) * S + j];
        sx += d.x; sy += d.y;
    }
    const float4 e2 = *(const float4*)&E2p[hh * S + j];  // (x0,y0,x1,y1)
    const float wa = 1.0f / sx, wb = 1.0f / sy;
    f16x2 qx, qy;
    qx[0] = (_Float16)(e2.x * wa); qx[1] = (_Float16)(e2.z * wb);
    qy[0] = (_Float16)(e2.y * wa); qy[1] = (_Float16)(e2.w * wb);
    wE2h[idx] = make_uint2(__builtin_bit_cast(unsigned int, qx),
                           __builtin_bit_cast(unsigned int, qy));
}

// ---------------------------------------------------------------------------
// k_attn R12: DECOUPLED K-quarters. Block = 256 thr = 4 M-waves sharing ONE
// Bs; grid (S/128, H, 4 K-quarters) = 1024 blocks. LDS = Bs dbuf 16K + wE2
// 4K = 20 KB -> 8 blocks/CU = 32 waves/CU; barriers couple only the 4 waves
// that share the staged tile, 8 independent blocks interleave per CU. No
// cross-quarter reduction — each block writes its z-partial; k_elu sums 4.
// ---------------------------------------------------------------------------
__global__ __launch_bounds__(256, 6) void k_attn(const unsigned int* __restrict__ bmT,
                                                 const float2* __restrict__ E1h,
                                                 const uint2* __restrict__ wE2h,
                                                 const unsigned short* __restrict__ hT,
                                                 float* __restrict__ outp) {
    __shared__ __align__(16) char smem[20480];   // Bs 2x8K | wE2s 4K
    const int h  = blockIdx.y;
    const int i0 = blockIdx.x * 128;
    const int z  = blockIdx.z;               // K-quarter (1024 j)
    const int t  = threadIdx.x;
    const int jbase = z * 1024;

    // ---- prologue: this quarter's 512 wE2 pairs (4 KB) into LDS ----
    uint2* wE2s = (uint2*)(smem + 16384);
    ((uint4*)wE2s)[t] = ((const uint4*)(wE2h + h * (S / 2) + (jbase >> 1)))[t & 255];

    const int lane = t & 63, mw = t >> 6;    // 4 M-waves, 32 rows each
    const int am = lane & 31, kh = lane >> 5;
    const int i  = i0 + mw * 32 + am;

    const float2 e1 = E1h[(size_t)i * H + h];
    f16x2 ea2, eb2;
    ea2[0] = ea2[1] = (_Float16)e1.x;
    eb2[0] = eb2[1] = (_Float16)e1.y;

    f32x16 acc0 = {0,0,0,0,0,0,0,0,0,0,0,0,0,0,0,0};
    f32x16 acc1 = {0,0,0,0,0,0,0,0,0,0,0,0,0,0,0,0};

    // staging: 4 threads/row, 2x16B each (64 rows x 64 j x 2B = 8 KB/tile)
    const int sf = t >> 2;             // f row 0..63
    const int c0 = t & 3;              // chunks c0 and c0+4
    unsigned short* Bq = (unsigned short*)smem;          // 2 bufs x 4096 shorts
    const unsigned short* hstage = hT + (size_t)(h * FOUT + sf) * PS + jbase;

    const unsigned int* bmcol = bmT + (jbase >> 5) * S + i;
    const uint2* e2s = wE2s + kh * 4;
    const unsigned int sh = kh * 8;

    // tile-0 prefetch
    uint4 va = *(const uint4*)(hstage + c0 * 8);
    uint4 vb = *(const uint4*)(hstage + 32 + c0 * 8);
    unsigned int bw0 = bmcol[0];
    unsigned int bw1 = bmcol[S];
    __syncthreads();   // wE2s ready

    for (int jt = 0; jt < 16; ++jt) {
        unsigned short* Bc = Bq + (jt & 1) * 4096;
        // write prefetched tile to LDS (XOR swizzle), then ONE barrier
        *(uint4*)&Bc[sf * 64 + ((c0 ^ (sf & 7)) * 8)]       = va;
        *(uint4*)&Bc[sf * 64 + (((c0 + 4) ^ (sf & 7)) * 8)] = vb;
        const unsigned int m0 = bw0, m1 = bw1;
        __syncthreads();
        // issue next-tile loads; they land during this tile's compute
        if (jt < 15) {
            va  = *(const uint4*)(hstage + (jt + 1) * 64 + c0 * 8);
            vb  = *(const uint4*)(hstage + (jt + 1) * 64 + 32 + c0 * 8);
            bw0 = bmcol[(2 * jt + 2) * S];
            bw1 = bmcol[(2 * jt + 3) * S];
        }
        unsigned int bys[4];
        bys[0] = (m0 >> sh) & 0xffu;
        bys[1] = (m0 >> (sh + 16)) & 0xffu;
        bys[2] = (m1 >> sh) & 0xffu;
        bys[3] = (m1 >> (sh + 16)) & 0xffu;
#pragma unroll
        for (int s = 0; s < 4; ++s) {
            const uint4 eA = *(const uint4*)(e2s + jt * 32 + s * 8);
            const uint4 eB = *(const uint4*)(e2s + jt * 32 + s * 8 + 2);
            const unsigned int by = bys[s];
            uint4 aw;
#define GAT_PAIR(pp, qxu, qyu, dst)                                               \
            {                                                                     \
                const f16x2 pa = ea2 * __builtin_bit_cast(f16x2, qxu);            \
                const f16x2 pb = eb2 * __builtin_bit_cast(f16x2, qyu);            \
                const f16x2 pm = __builtin_elementwise_max(pa, pb);               \
                const unsigned int b2 = (by >> (2 * pp)) & 3u;                    \
                const unsigned int vv = (b2 | (b2 << 15)) & 0x00010001u;          \
                const unsigned int mm = (vv << 14) - (vv << 10); /* x 0x3C00 */   \
                dst = __builtin_bit_cast(unsigned int,                            \
                      pm * __builtin_bit_cast(f16x2, mm));                        \
            }
            GAT_PAIR(0, eA.x, eA.y, aw.x)
            GAT_PAIR(1, eA.z, eA.w, aw.y)
            GAT_PAIR(2, eB.x, eB.y, aw.z)
            GAT_PAIR(3, eB.z, eB.w, aw.w)
#undef GAT_PAIR
            const int chunk = s * 2 + kh;
            const f16x8 a  = __builtin_bit_cast(f16x8, aw);
            const f16x8 b0 = *(const f16x8*)&Bc[am * 64 + ((chunk ^ (am & 7)) * 8)];
            const f16x8 b1 = *(const f16x8*)&Bc[(am + 32) * 64 + ((chunk ^ ((am + 32) & 7)) * 8)];
            acc0 = __builtin_amdgcn_mfma_f32_32x32x16_f16(a, b0, acc0, 0, 0, 0);
            acc1 = __builtin_amdgcn_mfma_f32_32x32x16_f16(a, b1, acc1, 0, 0, 0);
        }
    }

    // ---- direct store of this quarter's partial (no cross-q reduction) ----
    float* dst = outp + (size_t)z * (S * H * FOUT);
    // C layout (32x32): col = lane&31, row = (r&3) + 8*(r>>2) + 4*(lane>>5)
#pragma unroll
    for (int r = 0; r < 16; ++r) {
        const int il  = (r & 3) + 8 * (r >> 2) + 4 * kh;
        const int row = i0 + mw * 32 + il;
        dst[row * (H * FOUT) + h * FOUT + am]      = acc0[r];
        dst[row * (H * FOUT) + h * FOUT + 32 + am] = acc1[r];
    }
}

// ---------------------------------------------------------------------------
// k_elu: out = elu(p0 + p1 + p2 + p3)
// ---------------------------------------------------------------------------
__global__ __launch_bounds__(256) void k_elu(const float* __restrict__ outp,
                                             float* __restrict__ out) {
    const int idx = (blockIdx.x * 256 + threadIdx.x) * 4;
    float4 v = *(const float4*)&outp[idx];
#pragma unroll
    for (int z = 1; z < 4; ++z) {
        const float4 p = *(const float4*)&outp[(size_t)z * (S * H * FOUT) + idx];
        v.x += p.x; v.y += p.y; v.z += p.z; v.w += p.w;
    }
    v.x = v.x > 0.f ? v.x : __expf(v.x) - 1.f;
    v.y = v.y > 0.f ? v.y : __expf(v.y) - 1.f;
    v.z = v.z > 0.f ? v.z : __expf(v.z) - 1.f;
    v.w = v.w > 0.f ? v.w : __expf(v.w) - 1.f;
    *(float4*)&out[idx] = v;
}

extern "C" void kernel_launch(void* const* d_in, const int* in_sizes, int n_in,
                              void* d_out, int out_size, void* d_ws, size_t ws_size,
                              hipStream_t stream) {
    const float* X   = (const float*)d_in[0];  // [1,4096,128]
    const int*   adj = (const int*)d_in[1];    // [1,4096,4096]
    const float* W   = (const float*)d_in[2];  // [8,128,64]
    const float* a1  = (const float*)d_in[3];  // [8,64,1]
    const float* a2  = (const float*)d_in[4];  // [8,64,1]
    float* out = (float*)d_out;                // [4096, 512]

    char* ws = (char*)d_ws;
    unsigned short* hT   = (unsigned short*)ws;               // ≈4.03 MB fp16, PS stride
    float2*         E1h  = (float2*)(ws + 4325376);           // 256 KB [i][h]
    float2*         E2p  = (float2*)(ws + 4587520);           // 256 KB [h][j]
    float*          Dpart= (float*)(ws + 4849664);            // 4 MB [z32][h][j]
    unsigned int*   bmT  = (unsigned int*)(ws + 9043968);     // 2 MB [jword][i]
    uint2*          wE2h = (uint2*)(ws + 11141120);           // 128 KB [h][pair]
    float*          outp = (float*)(ws + 11272192);           // 32 MB [z4][i][hf]
    // total ~44 MB

    k_proj  <<<dim3(S / 64, H),       256, 0, stream>>>(X, W, a1, a2, hT, E1h, E2p);
    k_colsum<<<dim3(S / 64, S / 128), 256, 0, stream>>>(adj, E1h, E2p, Dpart, bmT);
    k_finish<<<dim3(H * S / 512),     256, 0, stream>>>(Dpart, E2p, wE2h);
    k_attn  <<<dim3(S / 128, H, 4),   256, 0, stream>>>(bmT, E1h, wE2h, hT, outp);
    k_elu   <<<dim3(S * H * FOUT / 1024), 256, 0, stream>>>(outp, out);
}

// Round 13
// 173.119 us; speedup vs baseline: 1.0302x; 1.0302x over previous
//
#include <hip/hip_runtime.h>

#define S 4096
#define PS 4128            // padded hT row stride in elems (breaks 8KB L1 aliasing)
#define FIN 128
#define FOUT 64
#define H 8
#define ALPHA 0.2f

typedef __attribute__((ext_vector_type(2)))  _Float16 f16x2;
typedef __attribute__((ext_vector_type(8)))  _Float16 f16x8;
typedef __attribute__((ext_vector_type(16))) float    f32x16;

__device__ __forceinline__ unsigned short f2h(float x) {
    return __builtin_bit_cast(unsigned short, (_Float16)x);  // RTNE
}
__device__ __forceinline__ float h2f(unsigned short u) {
    return (float)__builtin_bit_cast(_Float16, u);
}

// ---------------------------------------------------------------------------
// k_proj: h = X·W (fp32), hT[h][f][j] fp16 with padded row stride PS;
// f1=h·a1, f2=h·a2 -> E1h[i][h]=(e^f1,e^{a f1}); E2p[h][j]=(e^f2,e^{a f2}).
// ---------------------------------------------------------------------------
__global__ __launch_bounds__(256) void k_proj(const float* __restrict__ X,
                                              const float* __restrict__ W,
                                              const float* __restrict__ a1,
                                              const float* __restrict__ a2,
                                              unsigned short* __restrict__ hT,
                                              float2* __restrict__ E1h,
                                              float2* __restrict__ E2p) {
    __shared__ float xs[64][36];
    __shared__ float Ws[32][68];
    const int h  = blockIdx.y;
    const int j0 = blockIdx.x * 64;
    const int t  = threadIdx.x;
    const int fg = t & 15, rg = t >> 4;
    const int jr = t >> 2, q = t & 3;
    const int kw = t >> 3, cw = t & 7;
    float acc[4][4] = {};
#pragma unroll
    for (int k0 = 0; k0 < FIN; k0 += 32) {
        *(float4*)&xs[jr][q * 8]      = *(const float4*)&X[(j0 + jr) * FIN + k0 + q * 8];
        *(float4*)&xs[jr][q * 8 + 4]  = *(const float4*)&X[(j0 + jr) * FIN + k0 + q * 8 + 4];
        *(float4*)&Ws[kw][cw * 8]     = *(const float4*)&W[(h * FIN + k0 + kw) * FOUT + cw * 8];
        *(float4*)&Ws[kw][cw * 8 + 4] = *(const float4*)&W[(h * FIN + k0 + kw) * FOUT + cw * 8 + 4];
        __syncthreads();
#pragma unroll
        for (int kc = 0; kc < 8; ++kc) {
            float4 xr[4], wr[4];
#pragma unroll
            for (int r = 0; r < 4; ++r) xr[r] = *(const float4*)&xs[4 * rg + r][kc * 4];
#pragma unroll
            for (int kk = 0; kk < 4; ++kk) wr[kk] = *(const float4*)&Ws[kc * 4 + kk][fg * 4];
#pragma unroll
            for (int r = 0; r < 4; ++r) {
                const float* xp = (const float*)&xr[r];
#pragma unroll
                for (int kk = 0; kk < 4; ++kk) {
                    const float xv = xp[kk];
                    acc[r][0] += xv * wr[kk].x;
                    acc[r][1] += xv * wr[kk].y;
                    acc[r][2] += xv * wr[kk].z;
                    acc[r][3] += xv * wr[kk].w;
                }
            }
        }
        __syncthreads();
    }
    const float4 a1v = *(const float4*)&a1[h * FOUT + fg * 4];
    const float4 a2v = *(const float4*)&a2[h * FOUT + fg * 4];
#pragma unroll
    for (int r = 0; r < 4; ++r) {
        float p1 = acc[r][0] * a1v.x + acc[r][1] * a1v.y + acc[r][2] * a1v.z + acc[r][3] * a1v.w;
        float p2 = acc[r][0] * a2v.x + acc[r][1] * a2v.y + acc[r][2] * a2v.z + acc[r][3] * a2v.w;
#pragma unroll
        for (int off = 1; off < 16; off <<= 1) {
            p1 += __shfl_xor(p1, off, 64);
            p2 += __shfl_xor(p2, off, 64);
        }
        if (fg == 0) {
            const int row = j0 + 4 * rg + r;
            E1h[(size_t)row * H + h] = make_float2(__expf(p1), __expf(ALPHA * p1));
            E2p[h * S + row]         = make_float2(__expf(p2), __expf(ALPHA * p2));
        }
    }
#pragma unroll
    for (int c = 0; c < 4; ++c) {
        ushort4 pk;
        pk.x = f2h(acc[0][c]);
        pk.y = f2h(acc[1][c]);
        pk.z = f2h(acc[2][c]);
        pk.w = f2h(acc[3][c]);
        *(ushort4*)&hT[(size_t)(h * FOUT + fg * 4 + c) * PS + j0 + 4 * rg] = pk;
    }
}

// ---------------------------------------------------------------------------
// k_colsum: Dpart[z,h,j] = sum_{i in chunk z} adj(i,j)*max(E1x*E2x, E1y*E2y);
// packs adj into TRANSPOSED bitmask bmT[jword][i]. 8 adj rows in flight/wave,
// 2048 blocks = 8/CU. grid (S/64, S/128), 256 thr, 32 rows/wave.
// ---------------------------------------------------------------------------
__global__ __launch_bounds__(256) void k_colsum(const int* __restrict__ adj,
                                                const float2* __restrict__ E1h,
                                                const float2* __restrict__ E2p,
                                                float* __restrict__ Dpart,
                                                unsigned int* __restrict__ bmT) {
    __shared__ float red[4][H][64];
    const int j0    = blockIdx.x * 64;
    const int ibase = blockIdx.y * 128;
    const int t  = threadIdx.x;
    const int jl = t & 63;
    const int wv = __builtin_amdgcn_readfirstlane(t >> 6);
    float2 e2v[H];
    float Dl[H];
#pragma unroll
    for (int hh = 0; hh < H; ++hh) { e2v[hh] = E2p[hh * S + j0 + jl]; Dl[hh] = 0.f; }
    const int rowbase = ibase + wv * 32;
    for (int s = 0; s < 32; s += 8) {
        int av[8];
#pragma unroll
        for (int u = 0; u < 8; ++u)
            av[u] = adj[(size_t)(rowbase + s + u) * S + j0 + jl];
#pragma unroll
        for (int u = 0; u < 8; ++u) {
            const int row = rowbase + s + u;
            const float2* __restrict__ e1r = E1h + (size_t)row * H;  // wave-uniform
            const unsigned long long blt = __ballot(av[u] != 0);
            if (jl == 0) {
                bmT[(j0 >> 5) * S + row]       = (unsigned int)blt;
                bmT[((j0 >> 5) + 1) * S + row] = (unsigned int)(blt >> 32);
            }
            const float bf = av[u] != 0 ? 1.f : 0.f;
#pragma unroll
            for (int hh = 0; hh < H; ++hh) {
                const float2 e1 = e1r[hh];
                Dl[hh] = fmaf(bf, fmaxf(e1.x * e2v[hh].x, e1.y * e2v[hh].y), Dl[hh]);
            }
        }
    }
#pragma unroll
    for (int hh = 0; hh < H; ++hh) red[wv][hh][jl] = Dl[hh];
    __syncthreads();
    if (wv == 0) {
#pragma unroll
        for (int hh = 0; hh < H; ++hh) {
            const float sum = red[0][hh][jl] + red[1][hh][jl] +
                              red[2][hh][jl] + red[3][hh][jl];
            Dpart[(blockIdx.y * H + hh) * S + j0 + jl] = sum;
        }
    }
}

// ---------------------------------------------------------------------------
// k_finish: wE2h[h][pair] = { h2(qx_j,qx_j1), h2(qy_j,qy_j1) },
// q = E2pair / colsum  (w folded in, packed fp16 SoA pairs for k_attn)
// ---------------------------------------------------------------------------
__global__ __launch_bounds__(256) void k_finish(const float* __restrict__ Dpart,
                                                const float2* __restrict__ E2p,
                                                uint2* __restrict__ wE2h) {
    const int idx = blockIdx.x * 256 + threadIdx.x;   // pair index over H*S/2
    const int hh = idx >> 11, pp = idx & 2047;
    const int j = 2 * pp;
    float sx = 0.f, sy = 0.f;
#pragma unroll
    for (int z = 0; z < 32; ++z) {
        const float2 d = *(const float2*)&Dpart[(z * H + hh) * S + j];
        sx += d.x; sy += d.y;
    }
    const float4 e2 = *(const float4*)&E2p[hh * S + j];  // (x0,y0,x1,y1)
    const float wa = 1.0f / sx, wb = 1.0f / sy;
    f16x2 qx, qy;
    qx[0] = (_Float16)(e2.x * wa); qx[1] = (_Float16)(e2.z * wb);
    qy[0] = (_Float16)(e2.y * wa); qy[1] = (_Float16)(e2.w * wb);
    wE2h[idx] = make_uint2(__builtin_bit_cast(unsigned int, qx),
                           __builtin_bit_cast(unsigned int, qy));
}

// ---------------------------------------------------------------------------
// k_attn R13: R12 decoupled K-quarters + PACKED FP16 PARTIALS.
// Block = 256 thr = 4 M-waves sharing ONE Bs; grid (S/128, H, 4 K-quarters).
// Partial store: one u32 per (row, h, am) = fp16(acc0[r]) | fp16(acc1[r])<<16
// -> 4 MB per z-quarter (was 8 MB fp32): halves k_attn store + k_elu read HBM.
// Mask build via two integer multiplies (b2*0x8001 & 0x10001; vv*0x3C00).
// ---------------------------------------------------------------------------
__global__ __launch_bounds__(256, 6) void k_attn(const unsigned int* __restrict__ bmT,
                                                 const float2* __restrict__ E1h,
                                                 const uint2* __restrict__ wE2h,
                                                 const unsigned short* __restrict__ hT,
                                                 unsigned int* __restrict__ outp16) {
    __shared__ __align__(16) char smem[20480];   // Bs 2x8K | wE2s 4K
    const int h  = blockIdx.y;
    const int i0 = blockIdx.x * 128;
    const int z  = blockIdx.z;               // K-quarter (1024 j)
    const int t  = threadIdx.x;
    const int jbase = z * 1024;

    // ---- prologue: this quarter's 512 wE2 pairs (4 KB) into LDS ----
    uint2* wE2s = (uint2*)(smem + 16384);
    ((uint4*)wE2s)[t] = ((const uint4*)(wE2h + h * (S / 2) + (jbase >> 1)))[t & 255];

    const int lane = t & 63, mw = t >> 6;    // 4 M-waves, 32 rows each
    const int am = lane & 31, kh = lane >> 5;
    const int i  = i0 + mw * 32 + am;

    const float2 e1 = E1h[(size_t)i * H + h];
    f16x2 ea2, eb2;
    ea2[0] = ea2[1] = (_Float16)e1.x;
    eb2[0] = eb2[1] = (_Float16)e1.y;

    f32x16 acc0 = {0,0,0,0,0,0,0,0,0,0,0,0,0,0,0,0};
    f32x16 acc1 = {0,0,0,0,0,0,0,0,0,0,0,0,0,0,0,0};

    // staging: 4 threads/row, 2x16B each (64 rows x 64 j x 2B = 8 KB/tile)
    const int sf = t >> 2;             // f row 0..63
    const int c0 = t & 3;              // chunks c0 and c0+4
    unsigned short* Bq = (unsigned short*)smem;          // 2 bufs x 4096 shorts
    const unsigned short* hstage = hT + (size_t)(h * FOUT + sf) * PS + jbase;

    const unsigned int* bmcol = bmT + (jbase >> 5) * S + i;
    const uint2* e2s = wE2s + kh * 4;
    const unsigned int sh = kh * 8;

    // tile-0 prefetch
    uint4 va = *(const uint4*)(hstage + c0 * 8);
    uint4 vb = *(const uint4*)(hstage + 32 + c0 * 8);
    unsigned int bw0 = bmcol[0];
    unsigned int bw1 = bmcol[S];
    __syncthreads();   // wE2s ready

    for (int jt = 0; jt < 16; ++jt) {
        unsigned short* Bc = Bq + (jt & 1) * 4096;
        // write prefetched tile to LDS (XOR swizzle), then ONE barrier
        *(uint4*)&Bc[sf * 64 + ((c0 ^ (sf & 7)) * 8)]       = va;
        *(uint4*)&Bc[sf * 64 + (((c0 + 4) ^ (sf & 7)) * 8)] = vb;
        const unsigned int m0 = bw0, m1 = bw1;
        __syncthreads();
        // issue next-tile loads; they land during this tile's compute
        if (jt < 15) {
            va  = *(const uint4*)(hstage + (jt + 1) * 64 + c0 * 8);
            vb  = *(const uint4*)(hstage + (jt + 1) * 64 + 32 + c0 * 8);
            bw0 = bmcol[(2 * jt + 2) * S];
            bw1 = bmcol[(2 * jt + 3) * S];
        }
        unsigned int bys[4];
        bys[0] = (m0 >> sh) & 0xffu;
        bys[1] = (m0 >> (sh + 16)) & 0xffu;
        bys[2] = (m1 >> sh) & 0xffu;
        bys[3] = (m1 >> (sh + 16)) & 0xffu;
#pragma unroll
        for (int s = 0; s < 4; ++s) {
            const uint4 eA = *(const uint4*)(e2s + jt * 32 + s * 8);
            const uint4 eB = *(const uint4*)(e2s + jt * 32 + s * 8 + 2);
            const unsigned int by = bys[s];
            uint4 aw;
#define GAT_PAIR(pp, qxu, qyu, dst)                                               \
            {                                                                     \
                const f16x2 pa = ea2 * __builtin_bit_cast(f16x2, qxu);            \
                const f16x2 pb = eb2 * __builtin_bit_cast(f16x2, qyu);            \
                const f16x2 pm = __builtin_elementwise_max(pa, pb);               \
                const unsigned int b2 = (by >> (2 * pp)) & 3u;                    \
                const unsigned int vv = (b2 * 0x8001u) & 0x00010001u;             \
                const unsigned int mm = vv * 0x3C00u; /* fp16 1.0 per set bit */  \
                dst = __builtin_bit_cast(unsigned int,                            \
                      pm * __builtin_bit_cast(f16x2, mm));                        \
            }
            GAT_PAIR(0, eA.x, eA.y, aw.x)
            GAT_PAIR(1, eA.z, eA.w, aw.y)
            GAT_PAIR(2, eB.x, eB.y, aw.z)
            GAT_PAIR(3, eB.z, eB.w, aw.w)
#undef GAT_PAIR
            const int chunk = s * 2 + kh;
            const f16x8 a  = __builtin_bit_cast(f16x8, aw);
            const f16x8 b0 = *(const f16x8*)&Bc[am * 64 + ((chunk ^ (am & 7)) * 8)];
            const f16x8 b1 = *(const f16x8*)&Bc[(am + 32) * 64 + ((chunk ^ ((am + 32) & 7)) * 8)];
            acc0 = __builtin_amdgcn_mfma_f32_32x32x16_f16(a, b0, acc0, 0, 0, 0);
            acc1 = __builtin_amdgcn_mfma_f32_32x32x16_f16(a, b1, acc1, 0, 0, 0);
        }
    }

    // ---- packed fp16 partial store: u32 = (f=am) | (f=am+32)<<16 ----
    unsigned int* dst = outp16 + (size_t)z * (S * H * 32);
    // C layout (32x32): col = lane&31, row = (r&3) + 8*(r>>2) + 4*(lane>>5)
#pragma unroll
    for (int r = 0; r < 16; ++r) {
        const int il  = (r & 3) + 8 * (r >> 2) + 4 * kh;
        const int row = i0 + mw * 32 + il;
        const unsigned int pk =
            (unsigned int)f2h(acc0[r]) | ((unsigned int)f2h(acc1[r]) << 16);
        dst[row * (H * 32) + h * 32 + am] = pk;
    }
}

// ---------------------------------------------------------------------------
// k_elu: out = elu(sum of 4 packed-fp16 partials). Thread handles 4 u32s
// (am..am+3 of one (row,h)) -> two coalesced float4 stores (f=am*, f=am*+32).
// ---------------------------------------------------------------------------
__global__ __launch_bounds__(256) void k_elu(const unsigned int* __restrict__ outp16,
                                             float* __restrict__ out) {
    const int idx4 = blockIdx.x * 256 + threadIdx.x;   // uint4 index
    float x[4] = {0.f, 0.f, 0.f, 0.f}, y[4] = {0.f, 0.f, 0.f, 0.f};
#pragma unroll
    for (int z = 0; z < 4; ++z) {
        const uint4 p = ((const uint4*)(outp16 + (size_t)z * (S * H * 32)))[idx4];
        const unsigned int pv[4] = {p.x, p.y, p.z, p.w};
#pragma unroll
        for (int u = 0; u < 4; ++u) {
            x[u] += h2f((unsigned short)(pv[u] & 0xffffu));
            y[u] += h2f((unsigned short)(pv[u] >> 16));
        }
    }
    const int base = idx4 * 4;            // over [row][h][am32]
    const int row = base >> 8;            // /(H*32)
    const int hh  = (base >> 5) & 7;
    const int am0 = base & 31;
    float4 vx, vy;
    vx.x = x[0] > 0.f ? x[0] : __expf(x[0]) - 1.f;
    vx.y = x[1] > 0.f ? x[1] : __expf(x[1]) - 1.f;
    vx.z = x[2] > 0.f ? x[2] : __expf(x[2]) - 1.f;
    vx.w = x[3] > 0.f ? x[3] : __expf(x[3]) - 1.f;
    vy.x = y[0] > 0.f ? y[0] : __expf(y[0]) - 1.f;
    vy.y = y[1] > 0.f ? y[1] : __expf(y[1]) - 1.f;
    vy.z = y[2] > 0.f ? y[2] : __expf(y[2]) - 1.f;
    vy.w = y[3] > 0.f ? y[3] : __expf(y[3]) - 1.f;
    *(float4*)&out[row * (H * FOUT) + hh * FOUT + am0]      = vx;
    *(float4*)&out[row * (H * FOUT) + hh * FOUT + 32 + am0] = vy;
}

extern "C" void kernel_launch(void* const* d_in, const int* in_sizes, int n_in,
                              void* d_out, int out_size, void* d_ws, size_t ws_size,
                              hipStream_t stream) {
    const float* X   = (const float*)d_in[0];  // [1,4096,128]
    const int*   adj = (const int*)d_in[1];    // [1,4096,4096]
    const float* W   = (const float*)d_in[2];  // [8,128,64]
    const float* a1  = (const float*)d_in[3];  // [8,64,1]
    const float* a2  = (const float*)d_in[4];  // [8,64,1]
    float* out = (float*)d_out;                // [4096, 512]

    char* ws = (char*)d_ws;
    unsigned short* hT   = (unsigned short*)ws;               // ≈4.03 MB fp16, PS stride
    float2*         E1h  = (float2*)(ws + 4325376);           // 256 KB [i][h]
    float2*         E2p  = (float2*)(ws + 4587520);           // 256 KB [h][j]
    float*          Dpart= (float*)(ws + 4849664);            // 4 MB [z32][h][j]
    unsigned int*   bmT  = (unsigned int*)(ws + 9043968);     // 2 MB [jword][i]
    uint2*          wE2h = (uint2*)(ws + 11141120);           // 128 KB [h][pair]
    unsigned int*   outp16 = (unsigned int*)(ws + 11272192);  // 16 MB [z4][i][h][am]
    // total ~27.7 MB

    k_proj  <<<dim3(S / 64, H),       256, 0, stream>>>(X, W, a1, a2, hT, E1h, E2p);
    k_colsum<<<dim3(S / 64, S / 128), 256, 0, stream>>>(adj, E1h, E2p, Dpart, bmT);
    k_finish<<<dim3(H * S / 512),     256, 0, stream>>>(Dpart, E2p, wE2h);
    k_attn  <<<dim3(S / 128, H, 4),   256, 0, stream>>>(bmT, E1h, wE2h, hT, outp16);
    k_elu   <<<dim3(S * H * 32 / 1024), 256, 0, stream>>>(outp16, out);
}